// Round 2
// baseline (4056.318 us; speedup 1.0000x reference)
//
#include <hip/hip_runtime.h>
#include <hip/hip_cooperative_groups.h>
#include <cmath>

// (B, L, D, H) = (256, 32, 512, 512)
#define B_   256
#define L_   32
#define D_   512
#define H_   512
#define NH5  2560   // 5*H
#define N2   5120   // 2*NH5 : [al | ar] output width
#define SCALE 0.044194173824159216f  // 1/sqrt(H)

namespace cg = cooperative_groups;

// ---------------- persistent device state (re-initialized every launch) ----
__device__ float g_h [B_*L_*H_];          // [b][slot][j] node hidden
__device__ float g_c [B_*L_*H_];          // [b][slot][j] node cell
__device__ float g_al[(size_t)B_*L_*NH5]; // [b][slot][k] Wl @ h_slot
__device__ float g_ar[(size_t)B_*L_*NH5]; // [b][slot][k] Wr @ h_slot
__device__ float g_logit[B_*L_];          // pair logit keyed by LEFT slot
__device__ int   g_list[B_*L_];           // active slot list (sequence order)
__device__ int   g_count[B_];             // active node count
__device__ int   g_merged[B_];            // slot merged last iter (-1 done, -2 init)
__device__ int   g_mpos[B_];              // list position of last merge
__device__ int   g_rows[B_*L_];           // compact list of active (b,slot) rows
__device__ int   g_nrows;                 // its count
__device__ int   g_mlist[2][B_];          // ping-pong: batches merged this iter
__device__ int   g_cnt[2];                // their counts

// ---------------- init ------------------------------------------------------
__global__ __launch_bounds__(64) void zero_misc() {
  if (threadIdx.x == 0) { g_nrows = 0; g_cnt[0] = 0; g_cnt[1] = 0; }
}

__global__ __launch_bounds__(64) void init_state(const int* __restrict__ length) {
  int b = blockIdx.x, t = threadIdx.x;
  int len = length[b];
  if (t < L_) g_list[b*L_ + t] = t;
  if (t == 0) { g_count[b] = len; g_merged[b] = -2; g_mpos[b] = 0; }
  if (t < L_ && t < len) {               // only slots < length are ever read
    int idx = atomicAdd(&g_nrows, 1);
    g_rows[idx] = b*L_ + t;
  }
}

// ---------------- big row-compacted GEMMs (K=512, tile 128x128, 8x8) -------
// MODE 0: word GEMM  A=x rows   -> g_h|g_c (+b_word)   N=1024
// MODE 1: leaf GEMM  A=g_h rows -> g_al|g_ar           N=5120
template<int MODE>
__global__ __launch_bounds__(256) void gemm_big(
    const float* __restrict__ Aext,
    const float* __restrict__ Bm,
    const float* __restrict__ bias)
{
  const int NR = g_nrows;
  const int m0 = blockIdx.y * 128;
  if (m0 >= NR) return;                      // uniform early exit
  const int n0 = blockIdx.x * 128;

  const int tid = threadIdx.x;
  const int w = tid >> 6, l = tid & 63;
  const int tx = (w & 1) * 8 + (l & 7);      // 0..15 (n dir)
  const int ty = (w >> 1) * 8 + (l >> 3);    // 0..15 (m dir)

  __shared__ float As[8][128];
  __shared__ float Bs[8][128];

  const int ra = tid >> 1, qa = (tid & 1) * 4;   // 128 rows x 8 k staging

  const float* Abase = (MODE == 0) ? Aext : g_h;
  int mr = m0 + ra; if (mr >= NR) mr = NR - 1;
  const float* aptr = Abase + (size_t)g_rows[mr] * 512 + qa;

  const float* bptr;
  {
    int nrow = n0 + ra;
    if (MODE == 0) bptr = Bm + (size_t)nrow * 512 + qa;
    else bptr = Bm + (nrow < NH5 ? (size_t)nrow * 1024
                                 : (size_t)(nrow - NH5) * 1024 + 512) + qa;
  }

  float acc[8][8] = {};

  for (int k0 = 0; k0 < 512; k0 += 8) {
    float4 av = *(const float4*)(aptr + k0);
    float4 bv = *(const float4*)(bptr + k0);
    __syncthreads();
    As[qa+0][ra] = av.x; As[qa+1][ra] = av.y; As[qa+2][ra] = av.z; As[qa+3][ra] = av.w;
    Bs[qa+0][ra] = bv.x; Bs[qa+1][ra] = bv.y; Bs[qa+2][ra] = bv.z; Bs[qa+3][ra] = bv.w;
    __syncthreads();
#pragma unroll
    for (int k = 0; k < 8; k++) {
      float af[8], bf[8];
#pragma unroll
      for (int c = 0; c < 2; c++) {
        float4 t = *(const float4*)&As[k][ty*8 + 4*c];
        af[4*c+0]=t.x; af[4*c+1]=t.y; af[4*c+2]=t.z; af[4*c+3]=t.w;
      }
#pragma unroll
      for (int c = 0; c < 2; c++) {
        float4 t = *(const float4*)&Bs[k][tx*8 + 4*c];
        bf[4*c+0]=t.x; bf[4*c+1]=t.y; bf[4*c+2]=t.z; bf[4*c+3]=t.w;
      }
#pragma unroll
      for (int i = 0; i < 8; i++)
#pragma unroll
        for (int j = 0; j < 8; j++)
          acc[i][j] = fmaf(af[i], bf[j], acc[i][j]);
    }
  }

#pragma unroll
  for (int i = 0; i < 8; i++) {
    int mrow = m0 + ty*8 + i;
    if (mrow >= NR) continue;
    int crow = g_rows[mrow];
#pragma unroll
    for (int j = 0; j < 8; j++) {
      int n = n0 + tx*8 + j;
      float v = acc[i][j];
      if (MODE == 0) {
        v += bias[n];
        if (n < H_) g_h[(size_t)crow*H_ + n]        = v;
        else        g_c[(size_t)crow*H_ + (n - H_)] = v;
      } else {
        if (n < NH5) g_al[(size_t)crow*NH5 + n]         = v;
        else         g_ar[(size_t)crow*NH5 + (n - NH5)] = v;
      }
    }
  }
}

// ---------------- elementwise compose + logit ------------------------------
__device__ __forceinline__ float sigm(float x) { return 1.0f / (1.0f + expf(-x)); }

__device__ __forceinline__ float block_sum(float v, float* sred) {
#pragma unroll
  for (int off = 32; off > 0; off >>= 1) v += __shfl_down(v, off, 64);
  int w = threadIdx.x >> 6;
  if ((threadIdx.x & 63) == 0) sred[w] = v;
  __syncthreads();
  float r = sred[0] + sred[1] + sred[2] + sred[3];
  __syncthreads();
  return r;
}

__device__ float compose_pair(int b, int sl, int sr, bool store_hc,
                              const float* __restrict__ bc,
                              const float* __restrict__ q,
                              float* sred)
{
  const float* al = g_al + (size_t)(b*L_ + sl)*NH5;
  const float* ar = g_ar + (size_t)(b*L_ + sr)*NH5;
  float*       cl = g_c  + (size_t)(b*L_ + sl)*H_;
  const float* cr = g_c  + (size_t)(b*L_ + sr)*H_;
  float*       hl = g_h  + (size_t)(b*L_ + sl)*H_;
  float part = 0.f;
  for (int j = threadIdx.x; j < H_; j += 256) {
    float vi  = al[j]        + ar[j]        + bc[j];
    float vfl = al[H_+j]     + ar[H_+j]     + bc[H_+j];
    float vfr = al[2*H_+j]   + ar[2*H_+j]   + bc[2*H_+j];
    float vu  = al[3*H_+j]   + ar[3*H_+j]   + bc[3*H_+j];
    float vo  = al[4*H_+j]   + ar[4*H_+j]   + bc[4*H_+j];
    float c = cl[j]*sigm(vfl+1.f) + cr[j]*sigm(vfr+1.f) + tanhf(vu)*sigm(vi);
    float h = sigm(vo)*tanhf(c);
    if (store_hc) { cl[j] = c; hl[j] = h; }
    part += q[j]*h;
  }
  return block_sum(part, sred);
}

__global__ __launch_bounds__(256) void iter0_logits(const int* __restrict__ length,
                                                    const float* __restrict__ bc,
                                                    const float* __restrict__ q) {
  __shared__ float sred[4];
  int p = blockIdx.x, b = blockIdx.y;
  if (p >= length[b] - 1) return;            // inactive pair: never read
  float lg = compose_pair(b, p, p+1, false, bc, q, sred);
  if (threadIdx.x == 0) g_logit[b*L_ + p] = lg * SCALE;
}

// ---------------- fused 31-iteration cooperative loop ----------------------
__device__ void gemm_iter_tile(int tile, int nact, int par,
                               const float* __restrict__ Wc)
{
  __shared__ float As[16][64];
  __shared__ float Bs[16][64];
  const int mtile = tile / 80, ntile = tile % 80;   // N2/64 = 80 n-tiles
  const int m0 = mtile*64, n0 = ntile*64;
  const int tid = threadIdx.x;
  const int ra = tid >> 2, qa = (tid & 3) * 4;      // 64 rows x 16 k staging
  const int tx = tid & 15, ty = tid >> 4;

  int mr = m0 + ra; if (mr >= nact) mr = nact - 1;
  int bb = g_mlist[par][mr];
  int slot = g_merged[bb];
  const float* aptr = g_h + (size_t)(bb*L_ + slot)*H_ + qa;

  int nr = n0 + ra;
  const float* bptr = (nr < NH5) ? Wc + (size_t)nr*1024 + qa
                                 : Wc + (size_t)(nr - NH5)*1024 + 512 + qa;

  float acc[4][4] = {};
  for (int k0 = 0; k0 < 512; k0 += 16) {
    float4 av = *(const float4*)(aptr + k0);
    float4 bv = *(const float4*)(bptr + k0);
    __syncthreads();
    As[qa+0][ra] = av.x; As[qa+1][ra] = av.y; As[qa+2][ra] = av.z; As[qa+3][ra] = av.w;
    Bs[qa+0][ra] = bv.x; Bs[qa+1][ra] = bv.y; Bs[qa+2][ra] = bv.z; Bs[qa+3][ra] = bv.w;
    __syncthreads();
#pragma unroll
    for (int k = 0; k < 16; k++) {
      float4 a4 = *(const float4*)&As[k][ty*4];
      float4 b4 = *(const float4*)&Bs[k][tx*4];
      float af[4] = {a4.x, a4.y, a4.z, a4.w};
      float bf[4] = {b4.x, b4.y, b4.z, b4.w};
#pragma unroll
      for (int i = 0; i < 4; i++)
#pragma unroll
        for (int j = 0; j < 4; j++)
          acc[i][j] = fmaf(af[i], bf[j], acc[i][j]);
    }
  }

#pragma unroll
  for (int i = 0; i < 4; i++) {
    int mrow = m0 + ty*4 + i;
    if (mrow >= nact) continue;
    int bb2 = g_mlist[par][mrow];
    int sl2 = g_merged[bb2];
    size_t base = (size_t)(bb2*L_ + sl2)*NH5;
#pragma unroll
    for (int j = 0; j < 4; j++) {
      int n = n0 + tx*4 + j;
      if (n < NH5) g_al[base + n]         = acc[i][j];
      else         g_ar[base + (n - NH5)] = acc[i][j];
    }
  }
}

__global__ __launch_bounds__(256, 2) void loop_kernel(const int* __restrict__ length,
                                                      const float* __restrict__ bc,
                                                      const float* __restrict__ qv,
                                                      const float* __restrict__ Wc)
{
  cg::grid_group grid = cg::this_grid();
  __shared__ float sred[4];
  __shared__ int s_sel[3];
  const int bid = blockIdx.x, tid = threadIdx.x;

  for (int iter = 0; iter < L_-1; ++iter) {
    // ---------- phase S: per-batch logit refresh + select + merge ----------
    if (bid < B_) {
      int b = bid;
      if (b == 0 && tid == 255) g_cnt[(iter+1)&1] = 0;   // reset other parity
      int m     = g_count[b];
      int pslot = g_merged[b];
      int ppos  = g_mpos[b];
      int* list = g_list + b*L_;

      if (iter > 0 && pslot >= 0) {
        if (ppos > 0) {
          int sl = list[ppos-1], sr = list[ppos];
          float lg = compose_pair(b, sl, sr, false, bc, qv, sred);
          if (tid == 0) g_logit[b*L_ + sl] = lg * SCALE;
        }
        if (ppos < m-1) {
          int sl = list[ppos], sr = list[ppos+1];
          float lg = compose_pair(b, sl, sr, false, bc, qv, sred);
          if (tid == 0) g_logit[b*L_ + sl] = lg * SCALE;
        }
      }

      bool active = iter < (length[b] - 1);
      if (active) {
        __syncthreads();
        if (tid == 0) {
          float best = -1e30f; int bi = 0;
          for (int n = 0; n < m-1; n++) {       // list order: first-max wins
            float lg = g_logit[b*L_ + list[n]];
            if (lg > best) { best = lg; bi = n; }
          }
          s_sel[0] = bi; s_sel[1] = list[bi]; s_sel[2] = list[bi+1];
        }
        __syncthreads();
        int pos = s_sel[0], sl = s_sel[1], sr = s_sel[2];
        compose_pair(b, sl, sr, true, bc, qv, sred);
        if (tid == 0) {
          for (int n = pos+1; n < m-1; n++) g_list[b*L_ + n] = g_list[b*L_ + n+1];
          g_count[b]  = m - 1;
          g_merged[b] = sl;
          g_mpos[b]   = pos;
          int idx = atomicAdd(&g_cnt[iter&1], 1);
          g_mlist[iter&1][idx] = b;
        }
      } else if (tid == 0) {
        g_merged[b] = -1;
      }
    }
    grid.sync();

    // ---------- phase G: a_l/a_r GEMM for newly merged nodes ---------------
    if (iter < L_-2) {
      int par  = iter & 1;
      int nact = *((volatile int*)&g_cnt[par]);
      int mt   = (nact + 63) >> 6;
      int tiles = mt * 80;
      if (bid < tiles) gemm_iter_tile(bid, nact, par, Wc);
      grid.sync();
    }
  }
}

__global__ __launch_bounds__(256) void write_out(float* __restrict__ out) {
  int b = blockIdx.x;
  for (int j = threadIdx.x; j < H_; j += 256)
    out[(size_t)b*H_ + j] = g_h[(size_t)(b*L_)*H_ + j];   // node 0 lives in slot 0
}

// ---------------------------------------------------------------------------
extern "C" void kernel_launch(void* const* d_in, const int* in_sizes, int n_in,
                              void* d_out, int out_size, void* d_ws, size_t ws_size,
                              hipStream_t stream)
{
  (void)in_sizes; (void)n_in; (void)out_size; (void)d_ws; (void)ws_size;
  const float* x      = (const float*)d_in[0];
  const int*   length = (const int*)  d_in[1];
  const float* W_word = (const float*)d_in[2];
  const float* b_word = (const float*)d_in[3];
  const float* W_comp = (const float*)d_in[4];
  const float* b_comp = (const float*)d_in[5];
  const float* q      = (const float*)d_in[6];
  float* out = (float*)d_out;

  zero_misc<<<1, 64, 0, stream>>>();
  init_state<<<B_, 64, 0, stream>>>(length);

  gemm_big<0><<<dim3(1024/128, (B_*L_)/128), 256, 0, stream>>>(x, W_word, b_word);
  gemm_big<1><<<dim3(N2/128,   (B_*L_)/128), 256, 0, stream>>>(nullptr, W_comp, nullptr);

  iter0_logits<<<dim3(L_-1, B_), 256, 0, stream>>>(length, b_comp, q);

  {
    const int*   la = length;
    const float* ba = b_comp;
    const float* qa = q;
    const float* wa = W_comp;
    void* kargs[4] = { (void*)&la, (void*)&ba, (void*)&qa, (void*)&wa };
    hipLaunchCooperativeKernel((void*)loop_kernel, dim3(320), dim3(256),
                               kargs, 0, stream);
  }

  write_out<<<B_, 256, 0, stream>>>(out);
}

// Round 3
// 1680.762 us; speedup vs baseline: 2.4134x; 2.4134x over previous
//
#include <hip/hip_runtime.h>
#include <cmath>

// (B, L, D, H) = (256, 32, 512, 512)
#define B_   256
#define L_   32
#define H_   512
#define NH5  2560   // 5*H
#define N2   5120   // 2*NH5 : [al | ar] output width
#define SCALE 0.044194173824159216f  // 1/sqrt(H)

// ---------------- persistent device state (re-initialized every launch) ----
__device__ float g_h [B_*L_*H_];          // [b][slot][j] node hidden
__device__ float g_c [B_*L_*H_];          // [b][slot][j] node cell
__device__ float g_al[(size_t)B_*L_*NH5]; // [b][slot][k] Wl @ h_slot
__device__ float g_ar[(size_t)B_*L_*NH5]; // [b][slot][k] Wr @ h_slot
__device__ float g_logit[B_*L_];          // pair logit keyed by LEFT slot
__device__ int   g_list[B_*L_];           // active slot list (sequence order)
__device__ int   g_count[B_];             // active node count
__device__ int   g_merged[B_];            // slot merged last iter (-1 done, -2 init)
__device__ int   g_mpos[B_];              // list position of last merge
__device__ int   g_off[B_];               // exclusive prefix of lengths
__device__ int   g_rows[B_*L_];           // ordered compact list of active rows
__device__ int   g_nrows;
__device__ int   g_mlist[2][B_];          // batches merged this iter (parity)
__device__ int   g_cnt[2];

__device__ __forceinline__ float sigm(float x) { return 1.0f / (1.0f + expf(-x)); }

// ---------------- init: prefix-scan lengths, ordered row list --------------
__global__ __launch_bounds__(256) void scan_init(const int* __restrict__ length) {
  __shared__ int sw[4];
  const int t = threadIdx.x;
  const int len = length[t];
  int v = len;
#pragma unroll
  for (int off = 1; off < 64; off <<= 1) {
    int o = __shfl_up(v, off, 64);
    if ((t & 63) >= off) v += o;
  }
  if ((t & 63) == 63) sw[t >> 6] = v;
  __syncthreads();
  int base = 0;
  for (int w = 0; w < (t >> 6); w++) base += sw[w];
  const int incl = base + v;
  g_off[t] = incl - len;
  if (t == 255) g_nrows = incl;
  g_count[t] = len; g_merged[t] = -2; g_mpos[t] = 0;
  if (t == 0) { g_cnt[0] = 0; g_cnt[1] = 0; }
}

__global__ __launch_bounds__(32) void fill_rows() {
  const int b = blockIdx.x, t = threadIdx.x;
  g_list[b*L_ + t] = t;
  if (t < g_count[b]) g_rows[g_off[b] + t] = b*L_ + t;   // sorted by (b,slot)
}

// ---------------- big row-compacted GEMMs (tile 128x128, 8x8, prefetch) ----
// MODE 0: word GEMM  A=x rows   -> g_h|g_c (+b_word)   N=1024
// MODE 1: leaf GEMM  A=g_h rows -> g_al|g_ar           N=5120
template<int MODE>
__global__ __launch_bounds__(256) void gemm_big(
    const float* __restrict__ Aext,
    const float* __restrict__ Bm,
    const float* __restrict__ bias)
{
  const int NR = g_nrows;
  const int m0 = blockIdx.y * 128;
  if (m0 >= NR) return;                      // uniform early exit
  const int n0 = blockIdx.x * 128;

  const int tid = threadIdx.x;
  const int w = tid >> 6, l = tid & 63;
  const int tx = (w & 1) * 8 + (l & 7);      // 0..15 (n dir)
  const int ty = (w >> 1) * 8 + (l >> 3);    // 0..15 (m dir)

  __shared__ float As[8][128];
  __shared__ float Bs[8][128];

  const int ra = tid >> 1, qa = (tid & 1) * 4;   // 128 rows x 2 float4 chunks

  const float* Abase = (MODE == 0) ? Aext : g_h;
  int mr = m0 + ra; if (mr >= NR) mr = NR - 1;
  const float* aptr = Abase + (size_t)g_rows[mr] * 512 + qa;

  const float* bptr;
  {
    int nrow = n0 + ra;
    if (MODE == 0) bptr = Bm + (size_t)nrow * 512 + qa;
    else bptr = Bm + (nrow < NH5 ? (size_t)nrow * 1024
                                 : (size_t)(nrow - NH5) * 1024 + 512) + qa;
  }

  // register-prefetch pipeline: loads for k0+8 issue behind compute of k0
  float4 av = *(const float4*)(aptr);
  float4 bv = *(const float4*)(bptr);
  float acc[8][8] = {};

  for (int k0 = 0; k0 < 512; k0 += 8) {
    __syncthreads();
    As[qa+0][ra] = av.x; As[qa+1][ra] = av.y; As[qa+2][ra] = av.z; As[qa+3][ra] = av.w;
    Bs[qa+0][ra] = bv.x; Bs[qa+1][ra] = bv.y; Bs[qa+2][ra] = bv.z; Bs[qa+3][ra] = bv.w;
    __syncthreads();
    if (k0 + 8 < 512) {
      av = *(const float4*)(aptr + k0 + 8);
      bv = *(const float4*)(bptr + k0 + 8);
    }
#pragma unroll
    for (int k = 0; k < 8; k++) {
      float af[8], bf[8];
#pragma unroll
      for (int c = 0; c < 2; c++) {
        float4 t = *(const float4*)&As[k][ty*8 + 4*c];
        af[4*c+0]=t.x; af[4*c+1]=t.y; af[4*c+2]=t.z; af[4*c+3]=t.w;
      }
#pragma unroll
      for (int c = 0; c < 2; c++) {
        float4 t = *(const float4*)&Bs[k][tx*8 + 4*c];
        bf[4*c+0]=t.x; bf[4*c+1]=t.y; bf[4*c+2]=t.z; bf[4*c+3]=t.w;
      }
#pragma unroll
      for (int i = 0; i < 8; i++)
#pragma unroll
        for (int j = 0; j < 8; j++)
          acc[i][j] = fmaf(af[i], bf[j], acc[i][j]);
    }
  }

#pragma unroll
  for (int i = 0; i < 8; i++) {
    int mrow = m0 + ty*8 + i;
    if (mrow >= NR) continue;
    int crow = g_rows[mrow];
#pragma unroll
    for (int j = 0; j < 8; j++) {
      int n = n0 + tx*8 + j;
      float v = acc[i][j];
      if (MODE == 0) {
        v += bias[n];
        if (n < H_) g_h[(size_t)crow*H_ + n]        = v;
        else        g_c[(size_t)crow*H_ + (n - H_)] = v;
      } else {
        if (n < NH5) g_al[(size_t)crow*NH5 + n]         = v;
        else         g_ar[(size_t)crow*NH5 + (n - NH5)] = v;
      }
    }
  }
}

// ---------------- iteration-0 logits ---------------------------------------
__global__ __launch_bounds__(256) void iter0_logits(const int* __restrict__ length,
                                                    const float* __restrict__ bc,
                                                    const float* __restrict__ qv) {
  __shared__ float sred[4];
  const int p = blockIdx.x, b = blockIdx.y;
  if (p >= length[b] - 1) return;            // inactive pair: never read
  const float* al = g_al + (size_t)(b*L_ + p)*NH5;
  const float* ar = g_ar + (size_t)(b*L_ + p + 1)*NH5;
  const float* cl = g_c  + (size_t)(b*L_ + p)*H_;
  const float* cr = g_c  + (size_t)(b*L_ + p + 1)*H_;
  float part = 0.f;
#pragma unroll
  for (int jj = 0; jj < H_/256; jj++) {
    int j = threadIdx.x + jj*256;
    float vi  = al[j]       + ar[j]       + bc[j];
    float vfl = al[H_+j]    + ar[H_+j]    + bc[H_+j];
    float vfr = al[2*H_+j]  + ar[2*H_+j]  + bc[2*H_+j];
    float vu  = al[3*H_+j]  + ar[3*H_+j]  + bc[3*H_+j];
    float vo  = al[4*H_+j]  + ar[4*H_+j]  + bc[4*H_+j];
    float c = cl[j]*sigm(vfl+1.f) + cr[j]*sigm(vfr+1.f) + tanhf(vu)*sigm(vi);
    float h = sigm(vo)*tanhf(c);
    part = fmaf(qv[j], h, part);
  }
#pragma unroll
  for (int off = 32; off; off >>= 1) part += __shfl_down(part, off, 64);
  if ((threadIdx.x & 63) == 0) sred[threadIdx.x >> 6] = part;
  __syncthreads();
  if (threadIdx.x == 0)
    g_logit[b*L_ + p] = (sred[0]+sred[1]+sred[2]+sred[3]) * SCALE;
}

// ---------------- per-iteration select + merge -----------------------------
__global__ __launch_bounds__(256) void select_merge(int iter,
    const int* __restrict__ length,
    const float* __restrict__ bc,
    const float* __restrict__ qv)
{
  __shared__ float sred[4];
  __shared__ int s_sel[3];
  const int b = blockIdx.x, tid = threadIdx.x;
  if (b == 0 && tid == 0) g_cnt[(iter & 1) ^ 1] = 0;  // reset next iter's counter

  const int m     = g_count[b];
  const int pslot = g_merged[b];
  const int ppos  = g_mpos[b];
  int* list = g_list + b*L_;

  // ---- refresh the <=2 dirty pairs, half-block each ----
  if (iter > 0 && pslot >= 0) {
    const int half = tid >> 7, lt = tid & 127;
    int sl = -1, sr = -1;
    if (half == 0) { if (ppos > 0)     { sl = list[ppos-1]; sr = list[ppos];   } }
    else           { if (ppos < m - 1) { sl = list[ppos];   sr = list[ppos+1]; } }
    float part = 0.f;
    if (sl >= 0) {
      const float* al = g_al + (size_t)(b*L_+sl)*NH5;
      const float* ar = g_ar + (size_t)(b*L_+sr)*NH5;
      const float* cl = g_c  + (size_t)(b*L_+sl)*H_;
      const float* cr = g_c  + (size_t)(b*L_+sr)*H_;
#pragma unroll
      for (int jj = 0; jj < H_/128; jj++) {
        int j = lt + jj*128;
        float vi  = al[j]       + ar[j]       + bc[j];
        float vfl = al[H_+j]    + ar[H_+j]    + bc[H_+j];
        float vfr = al[2*H_+j]  + ar[2*H_+j]  + bc[2*H_+j];
        float vu  = al[3*H_+j]  + ar[3*H_+j]  + bc[3*H_+j];
        float vo  = al[4*H_+j]  + ar[4*H_+j]  + bc[4*H_+j];
        float c = cl[j]*sigm(vfl+1.f) + cr[j]*sigm(vfr+1.f) + tanhf(vu)*sigm(vi);
        float h = sigm(vo)*tanhf(c);
        part = fmaf(qv[j], h, part);
      }
    }
#pragma unroll
    for (int off = 32; off; off >>= 1) part += __shfl_down(part, off, 64);
    if ((tid & 63) == 0) sred[tid >> 6] = part;
    __syncthreads();
    if (tid == 0   && ppos > 0)     g_logit[b*L_ + list[ppos-1]] = (sred[0]+sred[1])*SCALE;
    if (tid == 128 && ppos < m - 1) g_logit[b*L_ + list[ppos]]   = (sred[2]+sred[3])*SCALE;
  }

  const bool active = iter < (length[b] - 1);
  if (!active) { if (tid == 0) g_merged[b] = -1; return; }

  __syncthreads();   // refreshed g_logit visible block-wide

  // ---- wave-parallel argmax, first-max tie-break (lowest index) ----
  if (tid < 64) {
    float lg = -1e30f; int idx = tid;
    if (tid < m - 1) lg = g_logit[b*L_ + list[tid]];
#pragma unroll
    for (int off = 32; off; off >>= 1) {
      float olg = __shfl_down(lg, off, 64);
      int   oid = __shfl_down(idx, off, 64);
      if (olg > lg || (olg == lg && oid < idx)) { lg = olg; idx = oid; }
    }
    if (tid == 0) { s_sel[0] = idx; s_sel[1] = list[idx]; s_sel[2] = list[idx+1]; }
  }
  __syncthreads();
  const int pos = s_sel[0], sl = s_sel[1], sr = s_sel[2];

  // ---- merge compose (store h,c; no reduction needed) ----
  {
    const float* al = g_al + (size_t)(b*L_+sl)*NH5;
    const float* ar = g_ar + (size_t)(b*L_+sr)*NH5;
    float*       cl = g_c  + (size_t)(b*L_+sl)*H_;
    const float* cr = g_c  + (size_t)(b*L_+sr)*H_;
    float*       hl = g_h  + (size_t)(b*L_+sl)*H_;
#pragma unroll
    for (int jj = 0; jj < H_/256; jj++) {
      int j = tid + jj*256;
      float vi  = al[j]       + ar[j]       + bc[j];
      float vfl = al[H_+j]    + ar[H_+j]    + bc[H_+j];
      float vfr = al[2*H_+j]  + ar[2*H_+j]  + bc[2*H_+j];
      float vu  = al[3*H_+j]  + ar[3*H_+j]  + bc[3*H_+j];
      float vo  = al[4*H_+j]  + ar[4*H_+j]  + bc[4*H_+j];
      float c = cl[j]*sigm(vfl+1.f) + cr[j]*sigm(vfr+1.f) + tanhf(vu)*sigm(vi);
      float h = sigm(vo)*tanhf(c);
      cl[j] = c; hl[j] = h;                  // same-thread j: no RAW hazard
    }
  }
  if (tid == 0) {
    for (int n = pos+1; n < m-1; n++) list[n] = list[n+1];
    g_count[b]  = m - 1;
    g_merged[b] = sl;
    g_mpos[b]   = pos;
    int k = atomicAdd(&g_cnt[iter & 1], 1);
    g_mlist[iter & 1][k] = b;
  }
}

// ---------------- per-iteration a_l/a_r GEMM (M=nact, 32x64 tiles) ---------
__global__ __launch_bounds__(256) void gemm_iter(int par, const float* __restrict__ Wc)
{
  const int nact = g_cnt[par];
  const int m0 = blockIdx.y * 32;
  if (m0 >= nact) return;                    // uniform early exit (handles nact=0)
  const int n0 = blockIdx.x * 64;
  const int tid = threadIdx.x;

  __shared__ float As[32][32];   // [k][m]
  __shared__ float Bs[32][64];   // [k][n]

  // A staging: 32 rows x 32 k, 1 float4/thread (coalesced 128B per row)
  const int ra = tid >> 3, qa = (tid & 7) * 4;
  int mr = m0 + ra; if (mr >= nact) mr = nact - 1;
  const int bbA = g_mlist[par][mr];
  const float* aptr = g_h + (size_t)(bbA*L_ + g_merged[bbA]) * 512 + qa;

  // B staging: 64 rows x 32 k, 8 consecutive floats/thread
  const int rb = tid >> 2, qb = (tid & 3) * 8;
  const int nr = n0 + rb;
  const float* bptr = (nr < NH5) ? Wc + (size_t)nr * 1024 + qb
                                 : Wc + (size_t)(nr - NH5) * 1024 + 512 + qb;

  const int tx = tid & 15, ty = tid >> 4;    // 16 n-groups x 16 m-groups

  float4 av  = *(const float4*)(aptr);
  float4 bv0 = *(const float4*)(bptr);
  float4 bv1 = *(const float4*)(bptr + 4);
  float acc[2][4] = {};

  for (int k0 = 0; k0 < 512; k0 += 32) {
    __syncthreads();
    As[qa+0][ra] = av.x;  As[qa+1][ra] = av.y;  As[qa+2][ra] = av.z;  As[qa+3][ra] = av.w;
    Bs[qb+0][rb] = bv0.x; Bs[qb+1][rb] = bv0.y; Bs[qb+2][rb] = bv0.z; Bs[qb+3][rb] = bv0.w;
    Bs[qb+4][rb] = bv1.x; Bs[qb+5][rb] = bv1.y; Bs[qb+6][rb] = bv1.z; Bs[qb+7][rb] = bv1.w;
    __syncthreads();
    if (k0 + 32 < 512) {
      av  = *(const float4*)(aptr + k0 + 32);
      bv0 = *(const float4*)(bptr + k0 + 32);
      bv1 = *(const float4*)(bptr + k0 + 36);
    }
#pragma unroll
    for (int k = 0; k < 32; k++) {
      float2 a2 = *(const float2*)&As[k][ty*2];
      float4 b4 = *(const float4*)&Bs[k][tx*4];
      acc[0][0] = fmaf(a2.x, b4.x, acc[0][0]);
      acc[0][1] = fmaf(a2.x, b4.y, acc[0][1]);
      acc[0][2] = fmaf(a2.x, b4.z, acc[0][2]);
      acc[0][3] = fmaf(a2.x, b4.w, acc[0][3]);
      acc[1][0] = fmaf(a2.y, b4.x, acc[1][0]);
      acc[1][1] = fmaf(a2.y, b4.y, acc[1][1]);
      acc[1][2] = fmaf(a2.y, b4.z, acc[1][2]);
      acc[1][3] = fmaf(a2.y, b4.w, acc[1][3]);
    }
  }

#pragma unroll
  for (int i = 0; i < 2; i++) {
    int mrow = m0 + ty*2 + i;
    if (mrow >= nact) continue;
    int bb = g_mlist[par][mrow];
    size_t base = (size_t)(bb*L_ + g_merged[bb]) * NH5;
    int n = n0 + tx*4;                       // 4-chunks never straddle NH5 (2560%64==0)
    float4 v = make_float4(acc[i][0], acc[i][1], acc[i][2], acc[i][3]);
    if (n < NH5) *(float4*)(g_al + base + n)         = v;
    else         *(float4*)(g_ar + base + (n - NH5)) = v;
  }
}

__global__ __launch_bounds__(256) void write_out(float* __restrict__ out) {
  int b = blockIdx.x;
  for (int j = threadIdx.x; j < H_; j += 256)
    out[(size_t)b*H_ + j] = g_h[(size_t)(b*L_)*H_ + j];   // node 0 lives in slot 0
}

// ---------------------------------------------------------------------------
extern "C" void kernel_launch(void* const* d_in, const int* in_sizes, int n_in,
                              void* d_out, int out_size, void* d_ws, size_t ws_size,
                              hipStream_t stream)
{
  (void)in_sizes; (void)n_in; (void)out_size; (void)d_ws; (void)ws_size;
  const float* x      = (const float*)d_in[0];
  const int*   length = (const int*)  d_in[1];
  const float* W_word = (const float*)d_in[2];
  const float* b_word = (const float*)d_in[3];
  const float* W_comp = (const float*)d_in[4];
  const float* b_comp = (const float*)d_in[5];
  const float* q      = (const float*)d_in[6];
  float* out = (float*)d_out;

  scan_init<<<1, 256, 0, stream>>>(length);
  fill_rows<<<B_, 32, 0, stream>>>();

  gemm_big<0><<<dim3(1024/128, 64), 256, 0, stream>>>(x, W_word, b_word);
  gemm_big<1><<<dim3(N2/128,   64), 256, 0, stream>>>(nullptr, W_comp, nullptr);

  iter0_logits<<<dim3(L_-1, B_), 256, 0, stream>>>(length, b_comp, q);

  for (int i = 0; i < L_-1; i++) {
    select_merge<<<B_, 256, 0, stream>>>(i, length, b_comp, q);
    if (i < L_-2)
      gemm_iter<<<dim3(N2/64, 8), 256, 0, stream>>>(i & 1, W_comp);
  }

  write_out<<<B_, 256, 0, stream>>>(out);
}